// Round 1
// baseline (505.341 us; speedup 1.0000x reference)
//
#include <hip/hip_runtime.h>

namespace {
constexpr int Bn = 2, Dn = 48, Hn = 320, Wn = 640;
constexpr int R = 2, K = 5, K2 = 25, C3 = 75;
constexpr int TW = 64, TH = 4;
constexpr int LW = TW + 2 * R;   // 68
constexpr int LH = TH + 2 * R;   // 8
constexpr int NT = TW * TH;      // 256
constexpr int LTOT = LH * LW;    // 544
}

// One LGA pass: out[b,d,h,w] = sum_{ij} w0*x[d] + w1*x[d-1] + w2*x[d+1] over 5x5 window,
// zero-padded spatially and in disparity.
// Thread = one (b,h,w) pixel column over all d. Weights in 75 VGPRs (reused across 48 d).
// Rolling 3-plane LDS tile + rolling 3x25 register windows (25 LDS reads per d instead of 75).
__global__ __launch_bounds__(NT, 2)
void lga_pass(const float* __restrict__ x, const float* __restrict__ wt,
              float* __restrict__ out) {
    __shared__ float pl[3][LH][LW];

    const int tx = threadIdx.x;          // 0..63 (w)
    const int ty = threadIdx.y;          // 0..3  (h)
    const int tid = ty * TW + tx;

    const int w0pix = blockIdx.x * TW;
    const int h0pix = blockIdx.y * TH;
    const int b = blockIdx.z;

    const int gw = w0pix + tx;
    const int gh = h0pix + ty;

    const size_t ps = (size_t)Hn * Wn;

    // ---- load 75 per-pixel guidance weights into registers (coalesced along w) ----
    float wr[C3];
    {
        const float* wp = wt + (size_t)b * C3 * ps + (size_t)gh * Wn + gw;
#pragma unroll
        for (int c = 0; c < C3; ++c) wr[c] = wp[c * ps];
    }

    const float* xb = x + (size_t)b * Dn * ps;
    float* ob = out + (size_t)b * Dn * ps + (size_t)gh * Wn + gw;

    const int sh0 = h0pix - R;
    const int sw0 = w0pix - R;

    // stage one d-plane's (LH x LW) spatial tile into LDS slot (prologue only)
    auto stage_direct = [&](int dp, int slot) {
        const float* src = xb + (size_t)dp * ps;
        const bool pv = (dp >= 0) && (dp < Dn);
#pragma unroll
        for (int t = 0; t < 3; ++t) {
            int idx = tid + t * NT;
            if (t < 2 || idx < LTOT) {
                int rr = idx / LW;
                int cc = idx - rr * LW;
                int hh = sh0 + rr;
                int ww = sw0 + cc;
                float v = 0.f;
                if (pv && hh >= 0 && hh < Hn && ww >= 0 && ww < Wn)
                    v = src[(size_t)hh * Wn + ww];
                (&pl[slot][0][0])[idx] = v;
            }
        }
    };

    // read this thread's 5x5 window of a staged plane into registers
    auto loadwin = [&](float (&win)[K2], int slot) {
#pragma unroll
        for (int i = 0; i < K; ++i)
#pragma unroll
            for (int j = 0; j < K; ++j)
                win[i * K + j] = pl[slot][ty + i][tx + j];
    };

    // one d iteration. Roles (all compile-time at call sites):
    //   wm = window of plane d-1, wc = plane d, wp = plane d+1 (loaded here from slot_p)
    //   slot_stage = (d+2)%3 gets plane d+2 staged (global loads issued first to overlap)
    auto step = [&](int d, float (&wm)[K2], float (&wc)[K2], float (&wp)[K2],
                    int slot_p, int slot_stage) {
        // phase A: issue global loads for plane d+2 into registers
        float stg[3];
        const int dp2 = d + 2;
        const float* src = xb + (size_t)dp2 * ps;
        const bool pv = (dp2 < Dn);   // dp2 >= 2 always
#pragma unroll
        for (int t = 0; t < 3; ++t) {
            int idx = tid + t * NT;
            stg[t] = 0.f;
            if (t < 2 || idx < LTOT) {
                int rr = idx / LW;
                int cc = idx - rr * LW;
                int hh = sh0 + rr;
                int ww = sw0 + cc;
                if (pv && hh >= 0 && hh < Hn && ww >= 0 && ww < Wn)
                    stg[t] = src[(size_t)hh * Wn + ww];
            }
        }
        // phase B: pull plane d+1 window from LDS, compute, store out[d]
        loadwin(wp, slot_p);
        float acc = 0.f;
#pragma unroll
        for (int q = 0; q < K2; ++q) acc += wr[q] * wc[q];
#pragma unroll
        for (int q = 0; q < K2; ++q) acc += wr[K2 + q] * wm[q];
#pragma unroll
        for (int q = 0; q < K2; ++q) acc += wr[2 * K2 + q] * wp[q];
        ob[(size_t)d * ps] = acc;
        // phase C: commit staged plane d+2 to LDS (slot held plane d-1, already consumed)
#pragma unroll
        for (int t = 0; t < 3; ++t) {
            int idx = tid + t * NT;
            if (t < 2 || idx < LTOT) (&pl[slot_stage][0][0])[idx] = stg[t];
        }
        __syncthreads();
    };

    // prologue: planes 0,1 into slots 0,1; plane -1 window = zeros
    stage_direct(0, 0);
    stage_direct(1, 1);
    __syncthreads();

    float win0[K2], win1[K2], win2[K2];
    loadwin(win0, 0);
#pragma unroll
    for (int q = 0; q < K2; ++q) win2[q] = 0.f;

    // D=48, unroll by 3 so all rotation indices are static
    for (int d0 = 0; d0 < Dn; d0 += 3) {
        step(d0 + 0, win2, win0, win1, 1, 2);
        step(d0 + 1, win0, win1, win2, 2, 0);
        step(d0 + 2, win1, win2, win0, 0, 1);
    }
}

extern "C" void kernel_launch(void* const* d_in, const int* in_sizes, int n_in,
                              void* d_out, int out_size, void* d_ws, size_t ws_size,
                              hipStream_t stream) {
    const float* x = (const float*)d_in[0];
    const float* w = (const float*)d_in[1];
    // d_in[2] = radius (scalar, always 2 for this problem; hardcoded)
    float* out = (float*)d_out;
    float* tmp = (float*)d_ws;   // intermediate y (needs 78.6 MB; ws is scratch)

    dim3 block(TW, TH, 1);
    dim3 grid(Wn / TW, Hn / TH, Bn);

    // pass 1: x -> tmp; pass 2: tmp -> out (same weights)
    lga_pass<<<grid, block, 0, stream>>>(x, w, tmp);
    lga_pass<<<grid, block, 0, stream>>>(tmp, w, out);
}